// Round 1
// baseline (1108.462 us; speedup 1.0000x reference)
//
#include <hip/hip_runtime.h>
#include <cstddef>

#define GRID_S 8000
#define FDIM 512
#define NHEAD 8
#define HD 64
#define KNN 32
#define NB 4

// ---------------- Projection GEMM: Y[m,n] = sum_k X[m,k] * W[n,k] ----------------
// X: [M=32000, 512], W: [512, 512] (row-major; we need x @ W^T so both are row-dots)
#define BM 64
#define BN 64
#define BK 32
#define LDSP 68   // padded row stride (words): keeps float4 alignment, 2-way banks on reads

__global__ __launch_bounds__(256) void proj_gemm(const float* __restrict__ X,
                                                 const float* __restrict__ W,
                                                 float* __restrict__ Y) {
    __shared__ float Xs[BK][LDSP];
    __shared__ float Ws[BK][LDSP];
    const int tid = threadIdx.x;
    const int bm = blockIdx.x * BM;
    const int bn = blockIdx.y * BN;
    const int ty = tid >> 4;   // 0..15
    const int tx = tid & 15;   // 0..15
    float acc[4][4] = {};

    for (int k0 = 0; k0 < FDIM; k0 += BK) {
        // stage 64x32 tiles of X and W, transposed into LDS as [k][m]
        #pragma unroll
        for (int i = 0; i < 2; ++i) {
            const int idx = tid + i * 256;     // 0..511
            const int row = idx >> 3;          // 0..63
            const int c4  = (idx & 7) * 4;     // 0,4,...,28
            float4 xv = *(const float4*)(X + (size_t)(bm + row) * FDIM + k0 + c4);
            Xs[c4 + 0][row] = xv.x;
            Xs[c4 + 1][row] = xv.y;
            Xs[c4 + 2][row] = xv.z;
            Xs[c4 + 3][row] = xv.w;
            float4 wv = *(const float4*)(W + (size_t)(bn + row) * FDIM + k0 + c4);
            Ws[c4 + 0][row] = wv.x;
            Ws[c4 + 1][row] = wv.y;
            Ws[c4 + 2][row] = wv.z;
            Ws[c4 + 3][row] = wv.w;
        }
        __syncthreads();
        #pragma unroll
        for (int kk = 0; kk < BK; ++kk) {
            float4 a = *(const float4*)&Xs[kk][ty * 4];
            float4 b = *(const float4*)&Ws[kk][tx * 4];
            const float av[4] = {a.x, a.y, a.z, a.w};
            const float bv[4] = {b.x, b.y, b.z, b.w};
            #pragma unroll
            for (int i = 0; i < 4; ++i)
                #pragma unroll
                for (int j = 0; j < 4; ++j)
                    acc[i][j] = fmaf(av[i], bv[j], acc[i][j]);
        }
        __syncthreads();
    }
    #pragma unroll
    for (int i = 0; i < 4; ++i) {
        float4 r = {acc[i][0], acc[i][1], acc[i][2], acc[i][3]};
        *(float4*)(Y + (size_t)(bm + ty * 4 + i) * FDIM + bn + tx * 4) = r;
    }
}

// ---------------- KNN attention: one block per (b,s) ----------------
__global__ __launch_bounds__(256) void knn_attn(const float* __restrict__ q,
                                                const float* __restrict__ k,
                                                const float* __restrict__ v,
                                                const int* __restrict__ nbr,
                                                float* __restrict__ out) {
    __shared__ float qs[FDIM];
    __shared__ float wgt[NHEAD][KNN];
    __shared__ int nb[KNN];
    const int bs = blockIdx.x;          // b*S + s
    const int b = bs / GRID_S;
    const int s = bs - b * GRID_S;
    const int tid = threadIdx.x;

    // stage q row (so q may alias out: all q reads come from LDS after this sync)
    const float* qrow = q + (size_t)bs * FDIM;
    qs[tid] = qrow[tid];
    qs[tid + 256] = qrow[tid + 256];
    if (tid < KNN) nb[tid] = nbr[s * KNN + tid];
    __syncthreads();

    // scoring: thread (h, j) computes score of neighbor j for head h
    const int h = tid >> 5;             // 0..7
    const int j = tid & 31;             // 0..31
    const float* krow = k + ((size_t)b * GRID_S + nb[j]) * FDIM + h * HD;
    const float* qh = qs + h * HD;
    float sc = 0.f;
    #pragma unroll
    for (int d = 0; d < HD; d += 4) {
        float4 kv = *(const float4*)(krow + d);
        sc = fmaf(qh[d + 0], kv.x, sc);
        sc = fmaf(qh[d + 1], kv.y, sc);
        sc = fmaf(qh[d + 2], kv.z, sc);
        sc = fmaf(qh[d + 3], kv.w, sc);
    }
    sc *= 0.125f;   // Hd^-0.5

    // softmax over the 32 lanes of each h-group (xor masks <32 stay in-group)
    float mx = sc;
    #pragma unroll
    for (int o = 16; o > 0; o >>= 1) mx = fmaxf(mx, __shfl_xor(mx, o));
    float e = __expf(sc - mx);
    float sm = e;
    #pragma unroll
    for (int o = 16; o > 0; o >>= 1) sm += __shfl_xor(sm, o);
    wgt[h][j] = e / sm;
    __syncthreads();

    // output: thread t computes out[t] and out[t+256]; coalesced v reads
    const float* vbase = v + (size_t)b * GRID_S * FDIM;
    const int h0 = tid >> 6;            // head of feature tid
    const int h1 = 4 + h0;              // head of feature tid+256
    float acc0 = 0.f, acc1 = 0.f;
    #pragma unroll
    for (int jj = 0; jj < KNN; ++jj) {
        const float* vrow = vbase + (size_t)nb[jj] * FDIM;
        acc0 = fmaf(wgt[h0][jj], vrow[tid], acc0);
        acc1 = fmaf(wgt[h1][jj], vrow[tid + 256], acc1);
    }
    float* orow = out + (size_t)bs * FDIM;
    orow[tid] = acc0;
    orow[tid + 256] = acc1;
}

extern "C" void kernel_launch(void* const* d_in, const int* in_sizes, int n_in,
                              void* d_out, int out_size, void* d_ws, size_t ws_size,
                              hipStream_t stream) {
    const float* x  = (const float*)d_in[0];
    const float* Wq = (const float*)d_in[1];
    const float* Wk = (const float*)d_in[2];
    const float* Wv = (const float*)d_in[3];
    const int*   nbr = (const int*)d_in[4];
    float* out = (float*)d_out;

    const size_t per_elems = (size_t)NB * GRID_S * FDIM;   // 16,384,000
    const size_t per_bytes = per_elems * sizeof(float);    // 65.5 MB

    float *qp, *kp, *vp;
    if (ws_size >= 3 * per_bytes) {
        qp = (float*)d_ws;
        kp = qp + per_elems;
        vp = kp + per_elems;
    } else {
        // fallback: stage q in d_out (attention consumes its own q row into LDS
        // before overwriting it), k/v in workspace
        qp = out;
        kp = (float*)d_ws;
        vp = kp + per_elems;
    }

    dim3 grid(NB * GRID_S / BM, FDIM / BN);   // (500, 8)
    proj_gemm<<<grid, 256, 0, stream>>>(x, Wq, qp);
    proj_gemm<<<grid, 256, 0, stream>>>(x, Wk, kp);
    proj_gemm<<<grid, 256, 0, stream>>>(x, Wv, vp);

    knn_attn<<<NB * GRID_S, 256, 0, stream>>>(qp, kp, vp, nbr, out);
}

// Round 2
// 553.234 us; speedup vs baseline: 2.0036x; 2.0036x over previous
//
#include <hip/hip_runtime.h>
#include <cstddef>
#include <cstdint>

#define GRID_S 8000
#define FDIM 512
#define NHEAD 8
#define HD 64
#define KNN 32
#define NB 4
#define M_TOT (NB * GRID_S)   // 32000

typedef __attribute__((ext_vector_type(8))) __bf16 bf16x8;
typedef __attribute__((ext_vector_type(4))) float f32x4;

// ---------------- fp32 -> bf16 (RTN-even), 4 elems/thread ----------------
__device__ inline ushort f2bf(float f) {
    uint32_t u = __builtin_bit_cast(uint32_t, f);
    uint32_t r = (u + 0x7fffu + ((u >> 16) & 1u)) >> 16;
    return (ushort)r;
}

__global__ __launch_bounds__(256) void cvt_bf16(const float* __restrict__ src,
                                                ushort* __restrict__ dst, int n4) {
    int i = blockIdx.x * 256 + threadIdx.x;
    if (i >= n4) return;
    float4 f = ((const float4*)src)[i];
    ushort4 o = { f2bf(f.x), f2bf(f.y), f2bf(f.z), f2bf(f.w) };
    ((ushort4*)dst)[i] = o;
}

// ---------------- bf16 MFMA GEMM (m97 structure): C[m,n] = sum_k A[m,k]*B[n,k] ----------
// A [M,512] bf16 row-major, B [512,512] bf16 row-major (= B^T input), C fp32.
#define TBM 128
#define TBN 128
#define TBK 32

__device__ inline void gload_lds16(const ushort* g, ushort* l) {
    __builtin_amdgcn_global_load_lds((const __attribute__((address_space(1))) uint32_t*)g,
                                     (__attribute__((address_space(3))) uint32_t*)l,
                                     16, 0, 0);
}

__global__ __launch_bounds__(256) void gemm_bf16(const ushort* __restrict__ A,
                                                 const ushort* __restrict__ B,
                                                 float* __restrict__ C) {
    __shared__ ushort As[TBM * TBK];
    __shared__ ushort Bs[TBN * TBK];
    const int tid = threadIdx.x;
    const int wv = tid >> 6;
    const int lane = tid & 63;
    const int bm = blockIdx.x * TBM;
    const int bn = blockIdx.y * TBN;
    const int wr = (wv >> 1) * 64;    // wave's 64x64 sub-tile
    const int wc = (wv & 1) * 64;
    f32x4 acc[4][4] = {};

    // staging: wave wv owns rows [wv*32, wv*32+32) of each tile.
    // one gload_lds16 = 64 lanes x 16B = 16 rows (lane>>2 = row, (lane&3)*8 = col chunk),
    // LDS dest is wave-uniform base + lane*16B which matches row-major [*][32] exactly.
    const int srow = wv * 32 + (lane >> 2);
    const int scol = (lane & 3) * 8;
    const int fr = lane & 15;          // fragment row/col within 16x16
    const int fk = (lane >> 4) * 8;    // fragment k-chunk

    for (int k0 = 0; k0 < FDIM; k0 += TBK) {
        const ushort* ga = A + (size_t)(bm + srow) * FDIM + k0 + scol;
        const ushort* gb = B + (size_t)(bn + srow) * FDIM + k0 + scol;
        gload_lds16(ga,              &As[(wv * 32) * TBK]);
        gload_lds16(ga + 16 * FDIM,  &As[(wv * 32 + 16) * TBK]);
        gload_lds16(gb,              &Bs[(wv * 32) * TBK]);
        gload_lds16(gb + 16 * FDIM,  &Bs[(wv * 32 + 16) * TBK]);
        __syncthreads();

        bf16x8 af[4], bfr[4];
        #pragma unroll
        for (int i = 0; i < 4; ++i) {
            af[i]  = *(const bf16x8*)&As[(wr + i * 16 + fr) * TBK + fk];
            bfr[i] = *(const bf16x8*)&Bs[(wc + i * 16 + fr) * TBK + fk];
        }
        #pragma unroll
        for (int i = 0; i < 4; ++i)
            #pragma unroll
            for (int j = 0; j < 4; ++j)
                acc[i][j] = __builtin_amdgcn_mfma_f32_16x16x32_bf16(af[i], bfr[j], acc[i][j], 0, 0, 0);
        __syncthreads();
    }

    // C/D layout: col = lane&15, row = (lane>>4)*4 + reg   [m89-verified]
    const int cr = (lane >> 4) * 4;
    const int cc = lane & 15;
    #pragma unroll
    for (int i = 0; i < 4; ++i)
        #pragma unroll
        for (int j = 0; j < 4; ++j) {
            float* cp = C + (size_t)(bm + wr + i * 16 + cr) * FDIM + bn + wc + j * 16 + cc;
            #pragma unroll
            for (int r = 0; r < 4; ++r)
                cp[(size_t)r * FDIM] = acc[i][j][r];
        }
}

// ---------------- fp32 fallback GEMM (only if workspace too small) ----------------
#define BM 64
#define BN 64
#define BK 32
#define LDSP 68

__global__ __launch_bounds__(256) void proj_gemm(const float* __restrict__ X,
                                                 const float* __restrict__ W,
                                                 float* __restrict__ Y) {
    __shared__ float Xs[BK][LDSP];
    __shared__ float Ws[BK][LDSP];
    const int tid = threadIdx.x;
    const int bm = blockIdx.x * BM;
    const int bn = blockIdx.y * BN;
    const int ty = tid >> 4;
    const int tx = tid & 15;
    float acc[4][4] = {};
    for (int k0 = 0; k0 < FDIM; k0 += BK) {
        #pragma unroll
        for (int i = 0; i < 2; ++i) {
            const int idx = tid + i * 256;
            const int row = idx >> 3;
            const int c4  = (idx & 7) * 4;
            float4 xv = *(const float4*)(X + (size_t)(bm + row) * FDIM + k0 + c4);
            Xs[c4 + 0][row] = xv.x; Xs[c4 + 1][row] = xv.y;
            Xs[c4 + 2][row] = xv.z; Xs[c4 + 3][row] = xv.w;
            float4 wv = *(const float4*)(W + (size_t)(bn + row) * FDIM + k0 + c4);
            Ws[c4 + 0][row] = wv.x; Ws[c4 + 1][row] = wv.y;
            Ws[c4 + 2][row] = wv.z; Ws[c4 + 3][row] = wv.w;
        }
        __syncthreads();
        #pragma unroll
        for (int kk = 0; kk < BK; ++kk) {
            float4 a = *(const float4*)&Xs[kk][ty * 4];
            float4 b = *(const float4*)&Ws[kk][tx * 4];
            const float av[4] = {a.x, a.y, a.z, a.w};
            const float bv[4] = {b.x, b.y, b.z, b.w};
            #pragma unroll
            for (int i = 0; i < 4; ++i)
                #pragma unroll
                for (int j = 0; j < 4; ++j)
                    acc[i][j] = fmaf(av[i], bv[j], acc[i][j]);
        }
        __syncthreads();
    }
    #pragma unroll
    for (int i = 0; i < 4; ++i) {
        float4 r = {acc[i][0], acc[i][1], acc[i][2], acc[i][3]};
        *(float4*)(Y + (size_t)(bm + ty * 4 + i) * FDIM + bn + tx * 4) = r;
    }
}

// ---------------- KNN attention: one block per (b,s) ----------------
__global__ __launch_bounds__(256) void knn_attn(const float* __restrict__ q,
                                                const float* __restrict__ k,
                                                const float* __restrict__ v,
                                                const int* __restrict__ nbr,
                                                float* __restrict__ out) {
    __shared__ float qs[FDIM];
    __shared__ float wgt[NHEAD][KNN];
    __shared__ int nb[KNN];
    const int bs = blockIdx.x;
    const int b = bs / GRID_S;
    const int s = bs - b * GRID_S;
    const int tid = threadIdx.x;

    const float* qrow = q + (size_t)bs * FDIM;
    qs[tid] = qrow[tid];
    qs[tid + 256] = qrow[tid + 256];
    if (tid < KNN) nb[tid] = nbr[s * KNN + tid];
    __syncthreads();

    const int h = tid >> 5;
    const int j = tid & 31;
    const float* krow = k + ((size_t)b * GRID_S + nb[j]) * FDIM + h * HD;
    const float* qh = qs + h * HD;
    float sc = 0.f;
    #pragma unroll
    for (int d = 0; d < HD; d += 4) {
        float4 kv = *(const float4*)(krow + d);
        sc = fmaf(qh[d + 0], kv.x, sc);
        sc = fmaf(qh[d + 1], kv.y, sc);
        sc = fmaf(qh[d + 2], kv.z, sc);
        sc = fmaf(qh[d + 3], kv.w, sc);
    }
    sc *= 0.125f;

    float mx = sc;
    #pragma unroll
    for (int o = 16; o > 0; o >>= 1) mx = fmaxf(mx, __shfl_xor(mx, o));
    float e = __expf(sc - mx);
    float sm = e;
    #pragma unroll
    for (int o = 16; o > 0; o >>= 1) sm += __shfl_xor(sm, o);
    wgt[h][j] = e / sm;
    __syncthreads();

    const float* vbase = v + (size_t)b * GRID_S * FDIM;
    const int h0 = tid >> 6;
    const int h1 = 4 + h0;
    float acc0 = 0.f, acc1 = 0.f;
    #pragma unroll
    for (int jj = 0; jj < KNN; ++jj) {
        const float* vrow = vbase + (size_t)nb[jj] * FDIM;
        acc0 = fmaf(wgt[h0][jj], vrow[tid], acc0);
        acc1 = fmaf(wgt[h1][jj], vrow[tid + 256], acc1);
    }
    float* orow = out + (size_t)bs * FDIM;
    orow[tid] = acc0;
    orow[tid + 256] = acc1;
}

extern "C" void kernel_launch(void* const* d_in, const int* in_sizes, int n_in,
                              void* d_out, int out_size, void* d_ws, size_t ws_size,
                              hipStream_t stream) {
    const float* x  = (const float*)d_in[0];
    const float* Wq = (const float*)d_in[1];
    const float* Wk = (const float*)d_in[2];
    const float* Wv = (const float*)d_in[3];
    const int*   nbr = (const int*)d_in[4];
    float* out = (float*)d_out;

    const size_t m_elems = (size_t)M_TOT * FDIM;        // 16,384,000
    const size_t w_elems = (size_t)FDIM * FDIM;         // 262,144
    const size_t qkv_bytes = m_elems * sizeof(float);   // 65,536,000
    const size_t conv_bytes = m_elems * 2 + 3 * w_elems * 2;  // 34,340,864

    char* ws = (char*)d_ws;

    if (ws_size >= conv_bytes + 2 * qkv_bytes) {
        // bf16 MFMA path
        ushort* xb  = (ushort*)ws;
        ushort* wqb = xb + m_elems;
        ushort* wkb = wqb + w_elems;
        ushort* wvb = wkb + w_elems;
        float* kp = (float*)(ws + conv_bytes);
        float* vp = kp + m_elems;
        float* qp = (ws_size >= conv_bytes + 3 * qkv_bytes) ? (vp + m_elems) : out;

        cvt_bf16<<<(int)(m_elems / 4 + 255) / 256, 256, 0, stream>>>(x, xb, (int)(m_elems / 4));
        cvt_bf16<<<(int)(w_elems / 4 + 255) / 256, 256, 0, stream>>>(Wq, wqb, (int)(w_elems / 4));
        cvt_bf16<<<(int)(w_elems / 4 + 255) / 256, 256, 0, stream>>>(Wk, wkb, (int)(w_elems / 4));
        cvt_bf16<<<(int)(w_elems / 4 + 255) / 256, 256, 0, stream>>>(Wv, wvb, (int)(w_elems / 4));

        dim3 grid(M_TOT / TBM, FDIM / TBN);   // (250, 4)
        gemm_bf16<<<grid, 256, 0, stream>>>(xb, wqb, qp);
        gemm_bf16<<<grid, 256, 0, stream>>>(xb, wkb, kp);
        gemm_bf16<<<grid, 256, 0, stream>>>(xb, wvb, vp);

        knn_attn<<<NB * GRID_S, 256, 0, stream>>>(qp, kp, vp, nbr, out);
    } else {
        // fp32 fallback (round-1 path)
        float *qp, *kp, *vp;
        if (ws_size >= 3 * qkv_bytes) {
            qp = (float*)ws; kp = qp + m_elems; vp = kp + m_elems;
        } else {
            qp = out; kp = (float*)ws; vp = kp + m_elems;
        }
        dim3 grid(M_TOT / BM, FDIM / BN);
        proj_gemm<<<grid, 256, 0, stream>>>(x, Wq, qp);
        proj_gemm<<<grid, 256, 0, stream>>>(x, Wk, kp);
        proj_gemm<<<grid, 256, 0, stream>>>(x, Wv, vp);
        knn_attn<<<NB * GRID_S, 256, 0, stream>>>(qp, kp, vp, nbr, out);
    }
}

// Round 3
// 258.925 us; speedup vs baseline: 4.2810x; 2.1367x over previous
//
#include <hip/hip_runtime.h>
#include <cstddef>
#include <cstdint>

#define GRID_S 8000
#define FDIM 512
#define NHEAD 8
#define HD 64
#define KNN 32
#define NB 4
#define M_TOT (NB * GRID_S)   // 32000

typedef __attribute__((ext_vector_type(8))) __bf16 bf16x8;
typedef __attribute__((ext_vector_type(4))) float f32x4;

// ---------------- helpers ----------------
__device__ inline ushort f2bf(float f) {            // RTN-even
    uint32_t u = __builtin_bit_cast(uint32_t, f);
    uint32_t r = (u + 0x7fffu + ((u >> 16) & 1u)) >> 16;
    return (ushort)r;
}
__device__ inline float bflo(uint32_t u) { return __builtin_bit_cast(float, u << 16); }
__device__ inline float bfhi(uint32_t u) { return __builtin_bit_cast(float, u & 0xffff0000u); }

__global__ __launch_bounds__(256) void cvt_bf16(const float* __restrict__ src,
                                                ushort* __restrict__ dst, int n4) {
    int i = blockIdx.x * 256 + threadIdx.x;
    if (i >= n4) return;
    float4 f = ((const float4*)src)[i];
    ushort4 o = { f2bf(f.x), f2bf(f.y), f2bf(f.z), f2bf(f.w) };
    ((ushort4*)dst)[i] = o;
}

// ---------------- bf16 MFMA GEMM (m97 structure): C[m,n] = sum_k A[m,k]*B[n,k] ----------
#define TBM 128
#define TBN 128
#define TBK 32

__device__ inline void gload_lds16(const ushort* g, ushort* l) {
    __builtin_amdgcn_global_load_lds((const __attribute__((address_space(1))) uint32_t*)g,
                                     (__attribute__((address_space(3))) uint32_t*)l,
                                     16, 0, 0);
}

template<int OUT_BF16>
__global__ __launch_bounds__(256) void gemm_mfma(const ushort* __restrict__ A,
                                                 const ushort* __restrict__ B,
                                                 void* __restrict__ Cv) {
    __shared__ ushort As[TBM * TBK];
    __shared__ ushort Bs[TBN * TBK];
    const int tid = threadIdx.x;
    const int wv = tid >> 6;
    const int lane = tid & 63;
    const int bm = blockIdx.x * TBM;
    const int bn = blockIdx.y * TBN;
    const int wr = (wv >> 1) * 64;
    const int wc = (wv & 1) * 64;
    f32x4 acc[4][4] = {};

    const int srow = wv * 32 + (lane >> 2);
    const int scol = (lane & 3) * 8;
    const int fr = lane & 15;
    const int fk = (lane >> 4) * 8;

    for (int k0 = 0; k0 < FDIM; k0 += TBK) {
        const ushort* ga = A + (size_t)(bm + srow) * FDIM + k0 + scol;
        const ushort* gb = B + (size_t)(bn + srow) * FDIM + k0 + scol;
        gload_lds16(ga,             &As[(wv * 32) * TBK]);
        gload_lds16(ga + 16 * FDIM, &As[(wv * 32 + 16) * TBK]);
        gload_lds16(gb,             &Bs[(wv * 32) * TBK]);
        gload_lds16(gb + 16 * FDIM, &Bs[(wv * 32 + 16) * TBK]);
        __syncthreads();

        bf16x8 af[4], bfr[4];
        #pragma unroll
        for (int i = 0; i < 4; ++i) {
            af[i]  = *(const bf16x8*)&As[(wr + i * 16 + fr) * TBK + fk];
            bfr[i] = *(const bf16x8*)&Bs[(wc + i * 16 + fr) * TBK + fk];
        }
        #pragma unroll
        for (int i = 0; i < 4; ++i)
            #pragma unroll
            for (int j = 0; j < 4; ++j)
                acc[i][j] = __builtin_amdgcn_mfma_f32_16x16x32_bf16(af[i], bfr[j], acc[i][j], 0, 0, 0);
        __syncthreads();
    }

    const int cr = (lane >> 4) * 4;
    const int cc = lane & 15;
    if constexpr (OUT_BF16) {
        ushort* Cb = (ushort*)Cv;
        #pragma unroll
        for (int i = 0; i < 4; ++i)
            #pragma unroll
            for (int j = 0; j < 4; ++j) {
                ushort* cp = Cb + (size_t)(bm + wr + i * 16 + cr) * FDIM + bn + wc + j * 16 + cc;
                #pragma unroll
                for (int r = 0; r < 4; ++r)
                    cp[(size_t)r * FDIM] = f2bf(acc[i][j][r]);
            }
    } else {
        float* Cf = (float*)Cv;
        #pragma unroll
        for (int i = 0; i < 4; ++i)
            #pragma unroll
            for (int j = 0; j < 4; ++j) {
                float* cp = Cf + (size_t)(bm + wr + i * 16 + cr) * FDIM + bn + wc + j * 16 + cc;
                #pragma unroll
                for (int r = 0; r < 4; ++r)
                    cp[(size_t)r * FDIM] = acc[i][j][r];
            }
    }
}

// ---------------- KNN attention v2: coalesced rows, bf16 k/v ----------------
// one block per (b,s); 4 waves.
// scoring: wave w handles neighbors j=8w..8w+7; lane covers features 8l..8l+7 of a FULL row.
// PV: wave w owns feature quarter [128w,128w+128); lane covers 2 features.
__global__ __launch_bounds__(256) void knn_attn2(const float* __restrict__ q,
                                                 const ushort* __restrict__ k,
                                                 const ushort* __restrict__ v,
                                                 const int* __restrict__ nbr,
                                                 float* __restrict__ out) {
    __shared__ float wgt[NHEAD][KNN + 1];   // +1 pad: PV broadcast reads land in distinct banks
    __shared__ int nb[KNN];
    const int bid = blockIdx.x;
    const int bs = (bid & 7) * (M_TOT / 8) + (bid >> 3);   // XCD swizzle (bijective: 32000%8==0)
    const int b = bs / GRID_S;
    const int s = bs - b * GRID_S;
    const int tid = threadIdx.x;
    const int lane = tid & 63;
    const int wv = tid >> 6;

    if (tid < KNN) nb[tid] = nbr[s * KNN + tid];

    // q fragment (features 8*lane .. 8*lane+7), coalesced global read; q may live in d_out:
    // all q reads happen before the first barrier, all out writes after the second.
    const float* qrow = q + (size_t)bs * FDIM + 8 * lane;
    float4 qa = *(const float4*)qrow;
    float4 qb = *(const float4*)(qrow + 4);
    const float qr[8] = {qa.x, qa.y, qa.z, qa.w, qb.x, qb.y, qb.z, qb.w};
    __syncthreads();

    // ---- scoring ----
    const ushort* kb = k + (size_t)b * GRID_S * FDIM + 8 * lane;
    int nbw[8];
    #pragma unroll
    for (int jj = 0; jj < 8; ++jj) nbw[jj] = nb[wv * 8 + jj];
    #pragma unroll
    for (int jj = 0; jj < 8; ++jj) {
        const uint4 kw = *(const uint4*)(kb + (size_t)nbw[jj] * FDIM);
        float p = qr[0] * bflo(kw.x) + qr[1] * bfhi(kw.x)
                + qr[2] * bflo(kw.y) + qr[3] * bfhi(kw.y)
                + qr[4] * bflo(kw.z) + qr[5] * bfhi(kw.z)
                + qr[6] * bflo(kw.w) + qr[7] * bfhi(kw.w);
        p += __shfl_xor(p, 1);
        p += __shfl_xor(p, 2);
        p += __shfl_xor(p, 4);
        if ((lane & 7) == 0) wgt[lane >> 3][wv * 8 + jj] = p * 0.125f;
    }
    __syncthreads();

    // ---- softmax: thread (h = tid>>5, j = tid&31); 32-lane groups stay in-wave ----
    {
        const int h = tid >> 5, j = tid & 31;
        float sc = wgt[h][j];
        float mx = sc;
        #pragma unroll
        for (int o = 16; o > 0; o >>= 1) mx = fmaxf(mx, __shfl_xor(mx, o));
        float e = __expf(sc - mx);
        float sm = e;
        #pragma unroll
        for (int o = 16; o > 0; o >>= 1) sm += __shfl_xor(sm, o);
        wgt[h][j] = e / sm;
    }
    __syncthreads();

    // ---- PV: feature quarter per wave; head of feature 128w+2l is tid>>5 ----
    const int myh = tid >> 5;
    const ushort* vb = v + (size_t)b * GRID_S * FDIM + 128 * wv + 2 * lane;
    float a0 = 0.f, a1 = 0.f;
    #pragma unroll 4
    for (int j = 0; j < KNN; ++j) {
        const uint32_t vw = *(const uint32_t*)(vb + (size_t)nb[j] * FDIM);
        const float w = wgt[myh][j];
        a0 = fmaf(w, bflo(vw), a0);
        a1 = fmaf(w, bfhi(vw), a1);
    }
    float2 o2 = {a0, a1};
    ((float2*)(out + (size_t)bs * FDIM))[tid] = o2;
}

extern "C" void kernel_launch(void* const* d_in, const int* in_sizes, int n_in,
                              void* d_out, int out_size, void* d_ws, size_t ws_size,
                              hipStream_t stream) {
    const float* x  = (const float*)d_in[0];
    const float* Wq = (const float*)d_in[1];
    const float* Wk = (const float*)d_in[2];
    const float* Wv = (const float*)d_in[3];
    const int*   nbr = (const int*)d_in[4];
    float* out = (float*)d_out;

    const size_t m_elems = (size_t)M_TOT * FDIM;   // 16,384,000
    const size_t w_elems = (size_t)FDIM * FDIM;    // 262,144

    // workspace layout (all bf16): x, Wq, Wk, Wv, k, v  -> ~100 MB
    ushort* xb  = (ushort*)d_ws;
    ushort* wqb = xb + m_elems;
    ushort* wkb = wqb + w_elems;
    ushort* wvb = wkb + w_elems;
    ushort* kbf = wvb + w_elems;
    ushort* vbf = kbf + m_elems;
    float*  qp  = out;   // q staged in d_out (safe: block bs reads q[bs] pre-barrier, writes out[bs] post-barrier)

    cvt_bf16<<<(int)(m_elems / 4 + 255) / 256, 256, 0, stream>>>(x, xb, (int)(m_elems / 4));
    cvt_bf16<<<(int)(w_elems / 4 + 255) / 256, 256, 0, stream>>>(Wq, wqb, (int)(w_elems / 4));
    cvt_bf16<<<(int)(w_elems / 4 + 255) / 256, 256, 0, stream>>>(Wk, wkb, (int)(w_elems / 4));
    cvt_bf16<<<(int)(w_elems / 4 + 255) / 256, 256, 0, stream>>>(Wv, wvb, (int)(w_elems / 4));

    dim3 grid(M_TOT / TBM, FDIM / TBN);   // (250, 4)
    gemm_mfma<0><<<grid, 256, 0, stream>>>(xb, wqb, (void*)qp);
    gemm_mfma<1><<<grid, 256, 0, stream>>>(xb, wkb, (void*)kbf);
    gemm_mfma<1><<<grid, 256, 0, stream>>>(xb, wvb, (void*)vbf);

    knn_attn2<<<M_TOT, 256, 0, stream>>>(qp, kbf, vbf, nbr, out);
}

// Round 4
// 248.668 us; speedup vs baseline: 4.4576x; 1.0412x over previous
//
#include <hip/hip_runtime.h>
#include <cstddef>
#include <cstdint>

#define GRID_S 8000
#define FDIM 512
#define NHEAD 8
#define HD 64
#define KNN 32
#define NB 4
#define M_TOT (NB * GRID_S)   // 32000

typedef __attribute__((ext_vector_type(8))) __bf16 bf16x8;
typedef __attribute__((ext_vector_type(4))) float f32x4;
typedef __attribute__((ext_vector_type(2))) float f32x2;

#if __has_builtin(__builtin_elementwise_fma)
#define FMA2(a,b,c) __builtin_elementwise_fma((a),(b),(c))
#else
#define FMA2(a,b,c) ((a)*(b)+(c))
#endif

// ---------------- helpers ----------------
__device__ inline ushort f2bf(float f) {            // RTN-even
    uint32_t u = __builtin_bit_cast(uint32_t, f);
    uint32_t r = (u + 0x7fffu + ((u >> 16) & 1u)) >> 16;
    return (ushort)r;
}
__device__ inline f32x2 unpk(uint32_t u) {          // packed bf16 pair -> 2 floats
    f32x2 r;
    r.x = __builtin_bit_cast(float, u << 16);
    r.y = __builtin_bit_cast(float, u & 0xffff0000u);
    return r;
}

// ---------------- fused fp32->bf16 convert: x and Wq|Wk|Wv into one buffer ----------
#define NX4 (M_TOT * FDIM / 4)   // 4,096,000 float4s of x
#define NW4 (FDIM * FDIM / 4)    // 65,536 float4s per W

__global__ __launch_bounds__(256) void cvt_all(const float* __restrict__ x,
                                               const float* __restrict__ Wq,
                                               const float* __restrict__ Wk,
                                               const float* __restrict__ Wv,
                                               ushort* __restrict__ xb,
                                               ushort* __restrict__ wb) {
    int i = blockIdx.x * 256 + threadIdx.x;
    if (i < NX4) {
        float4 f = ((const float4*)x)[i];
        ushort4 o = { f2bf(f.x), f2bf(f.y), f2bf(f.z), f2bf(f.w) };
        ((ushort4*)xb)[i] = o;
        return;
    }
    i -= NX4;
    const int which = i >> 16;           // /NW4
    const int off = i & (NW4 - 1);
    const float* w = (which == 0) ? Wq : (which == 1) ? Wk : Wv;
    float4 f = ((const float4*)w)[off];
    ushort4 o = { f2bf(f.x), f2bf(f.y), f2bf(f.z), f2bf(f.w) };
    ((ushort4*)wb)[which * NW4 + off] = o;
}

// ---------------- fused QKV bf16 MFMA GEMM: C[m,n] = sum_k A[m,k]*B[n,k] ----------
// A [32000,512] bf16, B [1536,512] bf16 (Wq|Wk|Wv rows). Segment 0 -> fp32 q,
// segments 1/2 -> bf16 k/v.
#define TBM 128
#define TBN 128
#define TBK 32

__device__ inline void gload_lds16(const ushort* g, ushort* l) {
    __builtin_amdgcn_global_load_lds((const __attribute__((address_space(1))) uint32_t*)g,
                                     (__attribute__((address_space(3))) uint32_t*)l,
                                     16, 0, 0);
}

__global__ __launch_bounds__(256) void gemm_qkv(const ushort* __restrict__ A,
                                                const ushort* __restrict__ B,
                                                float* __restrict__ qo,
                                                ushort* __restrict__ ko,
                                                ushort* __restrict__ vo) {
    __shared__ ushort As[TBM * TBK];
    __shared__ ushort Bs[TBN * TBK];
    const int tid = threadIdx.x;
    const int wv = tid >> 6;
    const int lane = tid & 63;
    const int bm = blockIdx.x * TBM;
    const int bn = blockIdx.y * TBN;          // 0..1535
    const int wr = (wv >> 1) * 64;
    const int wc = (wv & 1) * 64;
    f32x4 acc[4][4] = {};

    const int srow = wv * 32 + (lane >> 2);
    const int scol = (lane & 3) * 8;
    const int fr = lane & 15;
    const int fk = (lane >> 4) * 8;

    for (int k0 = 0; k0 < FDIM; k0 += TBK) {
        const ushort* ga = A + (size_t)(bm + srow) * FDIM + k0 + scol;
        const ushort* gb = B + (size_t)(bn + srow) * FDIM + k0 + scol;
        gload_lds16(ga,             &As[(wv * 32) * TBK]);
        gload_lds16(ga + 16 * FDIM, &As[(wv * 32 + 16) * TBK]);
        gload_lds16(gb,             &Bs[(wv * 32) * TBK]);
        gload_lds16(gb + 16 * FDIM, &Bs[(wv * 32 + 16) * TBK]);
        __syncthreads();

        bf16x8 af[4], bfr[4];
        #pragma unroll
        for (int i = 0; i < 4; ++i) {
            af[i]  = *(const bf16x8*)&As[(wr + i * 16 + fr) * TBK + fk];
            bfr[i] = *(const bf16x8*)&Bs[(wc + i * 16 + fr) * TBK + fk];
        }
        #pragma unroll
        for (int i = 0; i < 4; ++i)
            #pragma unroll
            for (int j = 0; j < 4; ++j)
                acc[i][j] = __builtin_amdgcn_mfma_f32_16x16x32_bf16(af[i], bfr[j], acc[i][j], 0, 0, 0);
        __syncthreads();
    }

    const int cr = (lane >> 4) * 4;
    const int cc = lane & 15;
    const int seg = blockIdx.y >> 2;                 // 0=q, 1=k, 2=v
    const int cn = (blockIdx.y & 3) * TBN;           // column within segment
    if (seg == 0) {
        #pragma unroll
        for (int i = 0; i < 4; ++i)
            #pragma unroll
            for (int j = 0; j < 4; ++j) {
                float* cp = qo + (size_t)(bm + wr + i * 16 + cr) * FDIM + cn + wc + j * 16 + cc;
                #pragma unroll
                for (int r = 0; r < 4; ++r)
                    cp[(size_t)r * FDIM] = acc[i][j][r];
            }
    } else {
        ushort* dst = (seg == 1) ? ko : vo;
        #pragma unroll
        for (int i = 0; i < 4; ++i)
            #pragma unroll
            for (int j = 0; j < 4; ++j) {
                ushort* cp = dst + (size_t)(bm + wr + i * 16 + cr) * FDIM + cn + wc + j * 16 + cc;
                #pragma unroll
                for (int r = 0; r < 4; ++r)
                    cp[(size_t)r * FDIM] = f2bf(acc[i][j][r]);
            }
    }
}

// ---------------- KNN attention v3: packed math, 16B loads everywhere ----------------
// one block per (b,s); 4 waves.
// scoring: wave w -> neighbors 8w..8w+7; lane -> features 8l..8l+7 (full row, 16B/lane).
// PV: lane -> chunk c = 16w + (l&15) (8 features), j-subgroup l>>4 (8 neighbors);
//     in-wave shfl_xor(16,32) reduce; lanes 0-15 write 2x float4.
__global__ __launch_bounds__(256) void knn_attn3(const float* __restrict__ q,
                                                 const ushort* __restrict__ k,
                                                 const ushort* __restrict__ v,
                                                 const int* __restrict__ nbr,
                                                 float* __restrict__ out) {
    __shared__ float wgt[NHEAD][KNN + 1];
    __shared__ int nbs[KNN];
    const int bid = blockIdx.x;
    const int bs = (bid & 7) * (M_TOT / 8) + (bid >> 3);   // bijective XCD swizzle
    const int b = bs / GRID_S;
    const int s = bs - b * GRID_S;
    const int tid = threadIdx.x;
    const int lane = tid & 63;
    const int wv = tid >> 6;

    if (tid < KNN) nbs[tid] = nbr[s * KNN + tid];

    // q fragment, pre-scaled by Hd^-0.5 (q may live in d_out: reads pre-barrier,
    // this block's out row written only at the end)
    const float* qrow = q + (size_t)bs * FDIM + 8 * lane;
    float4 qa = *(const float4*)qrow;
    float4 qb = *(const float4*)(qrow + 4);
    f32x2 q2[4] = {{qa.x, qa.y}, {qa.z, qa.w}, {qb.x, qb.y}, {qb.z, qb.w}};
    #pragma unroll
    for (int i = 0; i < 4; ++i) q2[i] *= 0.125f;
    __syncthreads();

    // ---- scoring ----
    const ushort* kb = k + (size_t)b * GRID_S * FDIM + 8 * lane;
    int nbw[8];
    #pragma unroll
    for (int jj = 0; jj < 8; ++jj) nbw[jj] = nbs[wv * 8 + jj];
    #pragma unroll
    for (int jj = 0; jj < 8; ++jj) {
        const uint4 kw = *(const uint4*)(kb + ((size_t)(uint32_t)nbw[jj] << 9));
        f32x2 a2 = q2[0] * unpk(kw.x);
        a2 = FMA2(q2[1], unpk(kw.y), a2);
        a2 = FMA2(q2[2], unpk(kw.z), a2);
        a2 = FMA2(q2[3], unpk(kw.w), a2);
        float p = a2.x + a2.y;
        p += __shfl_xor(p, 1);
        p += __shfl_xor(p, 2);
        p += __shfl_xor(p, 4);
        if ((lane & 7) == 0) wgt[lane >> 3][wv * 8 + jj] = p;
    }
    __syncthreads();

    // ---- softmax: thread (h = tid>>5, j = tid&31) ----
    {
        const int h = tid >> 5, j = tid & 31;
        float sc = wgt[h][j];
        float mx = sc;
        #pragma unroll
        for (int o = 16; o > 0; o >>= 1) mx = fmaxf(mx, __shfl_xor(mx, o));
        float e = __expf(sc - mx);
        float sm = e;
        #pragma unroll
        for (int o = 16; o > 0; o >>= 1) sm += __shfl_xor(sm, o);
        wgt[h][j] = e / sm;
    }
    __syncthreads();

    // ---- PV ----
    const int c = wv * 16 + (lane & 15);      // feature chunk (8 floats)
    const int jg = lane >> 4;                 // neighbor subgroup
    const int myh = c >> 3;
    int nbp[8];
    #pragma unroll
    for (int jj = 0; jj < 8; ++jj) nbp[jj] = nbs[jg * 8 + jj];
    const ushort* vb = v + (size_t)b * GRID_S * FDIM + 8 * c;
    f32x2 acc[4] = {};
    #pragma unroll
    for (int jj = 0; jj < 8; ++jj) {
        const uint4 vw = *(const uint4*)(vb + ((size_t)(uint32_t)nbp[jj] << 9));
        const float w = wgt[myh][jg * 8 + jj];
        f32x2 w2 = {w, w};
        acc[0] = FMA2(w2, unpk(vw.x), acc[0]);
        acc[1] = FMA2(w2, unpk(vw.y), acc[1]);
        acc[2] = FMA2(w2, unpk(vw.z), acc[2]);
        acc[3] = FMA2(w2, unpk(vw.w), acc[3]);
    }
    // reduce across the 4 j-subgroups (lanes differing in bits 4,5)
    #pragma unroll
    for (int o = 16; o <= 32; o <<= 1)
        #pragma unroll
        for (int r = 0; r < 4; ++r) {
            acc[r].x += __shfl_xor(acc[r].x, o);
            acc[r].y += __shfl_xor(acc[r].y, o);
        }
    if (lane < 16) {
        float* op = out + (size_t)bs * FDIM + 8 * c;
        float4 o0 = {acc[0].x, acc[0].y, acc[1].x, acc[1].y};
        float4 o1 = {acc[2].x, acc[2].y, acc[3].x, acc[3].y};
        *(float4*)op = o0;
        *(float4*)(op + 4) = o1;
    }
}

extern "C" void kernel_launch(void* const* d_in, const int* in_sizes, int n_in,
                              void* d_out, int out_size, void* d_ws, size_t ws_size,
                              hipStream_t stream) {
    const float* x  = (const float*)d_in[0];
    const float* Wq = (const float*)d_in[1];
    const float* Wk = (const float*)d_in[2];
    const float* Wv = (const float*)d_in[3];
    const int*   nbr = (const int*)d_in[4];
    float* out = (float*)d_out;

    const size_t m_elems = (size_t)M_TOT * FDIM;   // 16,384,000
    const size_t w_elems = (size_t)FDIM * FDIM;    // 262,144

    // workspace (bf16): xb, wb[3x512x512], k, v  ~= 100 MB
    ushort* xb  = (ushort*)d_ws;
    ushort* wb  = xb + m_elems;
    ushort* kbf = wb + 3 * w_elems;
    ushort* vbf = kbf + m_elems;
    float*  qp  = out;   // q staged in d_out

    cvt_all<<<(NX4 + 3 * NW4) / 256, 256, 0, stream>>>(x, Wq, Wk, Wv, xb, wb);

    dim3 grid(M_TOT / TBM, 3 * FDIM / TBN);   // (250, 12)
    gemm_qkv<<<grid, 256, 0, stream>>>(xb, wb, qp, kbf, vbf);

    knn_attn3<<<M_TOT, 256, 0, stream>>>(qp, kbf, vbf, nbr, out);
}

// Round 5
// 214.520 us; speedup vs baseline: 5.1672x; 1.1592x over previous
//
#include <hip/hip_runtime.h>
#include <cstddef>
#include <cstdint>

#define GRID_S 8000
#define FDIM 512
#define NHEAD 8
#define HD 64
#define KNN 32
#define NB 4
#define M_TOT (NB * GRID_S)   // 32000

typedef __attribute__((ext_vector_type(8))) __bf16 bf16x8;
typedef __attribute__((ext_vector_type(4))) float f32x4;
typedef __attribute__((ext_vector_type(2))) float f32x2;

#if __has_builtin(__builtin_elementwise_fma)
#define FMA2(a,b,c) __builtin_elementwise_fma((a),(b),(c))
#else
#define FMA2(a,b,c) ((a)*(b)+(c))
#endif

// ---------------- helpers ----------------
__device__ inline ushort f2bf(float f) {            // RTN-even
    uint32_t u = __builtin_bit_cast(uint32_t, f);
    uint32_t r = (u + 0x7fffu + ((u >> 16) & 1u)) >> 16;
    return (ushort)r;
}
__device__ inline f32x2 unpk(uint32_t u) {          // packed bf16 pair -> 2 floats
    f32x2 r;
    r.x = __builtin_bit_cast(float, u << 16);
    r.y = __builtin_bit_cast(float, u & 0xffff0000u);
    return r;
}

// ---------------- fused fp32->bf16 convert ----------------
#define NX4 (M_TOT * FDIM / 4)   // 4,096,000
#define NW4 (FDIM * FDIM / 4)    // 65,536

__global__ __launch_bounds__(256) void cvt_all(const float* __restrict__ x,
                                               const float* __restrict__ Wq,
                                               const float* __restrict__ Wk,
                                               const float* __restrict__ Wv,
                                               ushort* __restrict__ xb,
                                               ushort* __restrict__ wb) {
    int i = blockIdx.x * 256 + threadIdx.x;
    if (i < NX4) {
        float4 f = ((const float4*)x)[i];
        ushort4 o = { f2bf(f.x), f2bf(f.y), f2bf(f.z), f2bf(f.w) };
        ((ushort4*)xb)[i] = o;
        return;
    }
    i -= NX4;
    const int which = i >> 16;
    const int off = i & (NW4 - 1);
    const float* w = (which == 0) ? Wq : (which == 1) ? Wk : Wv;
    float4 f = ((const float4*)w)[off];
    ushort4 o = { f2bf(f.x), f2bf(f.y), f2bf(f.z), f2bf(f.w) };
    ((ushort4*)wb)[which * NW4 + off] = o;
}

// ---------------- fused QKV bf16 MFMA GEMM ----------------
#define TBM 128
#define TBN 128
#define TBK 32

__device__ inline void gload_lds16(const ushort* g, ushort* l) {
    __builtin_amdgcn_global_load_lds((const __attribute__((address_space(1))) uint32_t*)g,
                                     (__attribute__((address_space(3))) uint32_t*)l,
                                     16, 0, 0);
}

__global__ __launch_bounds__(256) void gemm_qkv(const ushort* __restrict__ A,
                                                const ushort* __restrict__ B,
                                                float* __restrict__ qo,
                                                ushort* __restrict__ ko,
                                                ushort* __restrict__ vo) {
    __shared__ ushort As[TBM * TBK];
    __shared__ ushort Bs[TBN * TBK];
    const int tid = threadIdx.x;
    const int wv = tid >> 6;
    const int lane = tid & 63;
    const int bm = blockIdx.x * TBM;
    const int bn = blockIdx.y * TBN;
    const int wr = (wv >> 1) * 64;
    const int wc = (wv & 1) * 64;
    f32x4 acc[4][4] = {};

    const int srow = wv * 32 + (lane >> 2);
    const int scol = (lane & 3) * 8;
    const int fr = lane & 15;
    const int fk = (lane >> 4) * 8;

    for (int k0 = 0; k0 < FDIM; k0 += TBK) {
        const ushort* ga = A + (size_t)(bm + srow) * FDIM + k0 + scol;
        const ushort* gb = B + (size_t)(bn + srow) * FDIM + k0 + scol;
        gload_lds16(ga,             &As[(wv * 32) * TBK]);
        gload_lds16(ga + 16 * FDIM, &As[(wv * 32 + 16) * TBK]);
        gload_lds16(gb,             &Bs[(wv * 32) * TBK]);
        gload_lds16(gb + 16 * FDIM, &Bs[(wv * 32 + 16) * TBK]);
        __syncthreads();

        bf16x8 af[4], bfr[4];
        #pragma unroll
        for (int i = 0; i < 4; ++i) {
            af[i]  = *(const bf16x8*)&As[(wr + i * 16 + fr) * TBK + fk];
            bfr[i] = *(const bf16x8*)&Bs[(wc + i * 16 + fr) * TBK + fk];
        }
        #pragma unroll
        for (int i = 0; i < 4; ++i)
            #pragma unroll
            for (int j = 0; j < 4; ++j)
                acc[i][j] = __builtin_amdgcn_mfma_f32_16x16x32_bf16(af[i], bfr[j], acc[i][j], 0, 0, 0);
        __syncthreads();
    }

    const int cr = (lane >> 4) * 4;
    const int cc = lane & 15;
    const int seg = blockIdx.y >> 2;
    const int cn = (blockIdx.y & 3) * TBN;
    if (seg == 0) {
        #pragma unroll
        for (int i = 0; i < 4; ++i)
            #pragma unroll
            for (int j = 0; j < 4; ++j) {
                float* cp = qo + (size_t)(bm + wr + i * 16 + cr) * FDIM + cn + wc + j * 16 + cc;
                #pragma unroll
                for (int r = 0; r < 4; ++r)
                    cp[(size_t)r * FDIM] = acc[i][j][r];
            }
    } else {
        ushort* dst = (seg == 1) ? ko : vo;
        #pragma unroll
        for (int i = 0; i < 4; ++i)
            #pragma unroll
            for (int j = 0; j < 4; ++j) {
                ushort* cp = dst + (size_t)(bm + wr + i * 16 + cr) * FDIM + cn + wc + j * 16 + cc;
                #pragma unroll
                for (int r = 0; r < 4; ++r)
                    cp[(size_t)r * FDIM] = f2bf(acc[i][j][r]);
            }
    }
}

// ---------------- KNN attention v4: wave-per-s, zero barriers, zero LDS ----------------
// lane l owns features [8l, 8l+8); lanes l with l>>3 == h form head h's 8-lane group.
// scoring: wave streams full 1KB k rows (SGPR row base, 16B/lane), 3-shfl reduce leaves
// score[h][j] in every lane of group h -> sc[j] registers.
// softmax: pure per-lane register math; 1/sum folded into final accumulators.
// PV: same streaming, weights already in-lane. No LDS, no __syncthreads.
__global__ __launch_bounds__(256) void knn_attn4(const float* __restrict__ q,
                                                 const ushort* __restrict__ k,
                                                 const ushort* __restrict__ v,
                                                 const int* __restrict__ nbr,
                                                 float* __restrict__ out) {
    const int bid = blockIdx.x;
    const int base = ((bid & 7) * (M_TOT / 32) + (bid >> 3)) * 4;   // bijective XCD swizzle, 4 consecutive s
    const int lane = threadIdx.x & 63;
    const int wv = threadIdx.x >> 6;
    const int bs = base + wv;
    const int b = bs / GRID_S;
    const int s = bs - b * GRID_S;

    const int* __restrict__ nrow = nbr + s * KNN;   // wave-uniform -> scalar loads

    // q fragment, pre-scaled (q lives in d_out; this wave alone reads/writes row bs)
    const float* qrow = q + (size_t)bs * FDIM + 8 * lane;
    float4 qa = *(const float4*)qrow;
    float4 qb = *(const float4*)(qrow + 4);
    f32x2 q2[4] = {{qa.x, qa.y}, {qa.z, qa.w}, {qb.x, qb.y}, {qb.z, qb.w}};
    #pragma unroll
    for (int i = 0; i < 4; ++i) q2[i] *= 0.125f;

    // ---- scoring: 32 coalesced row reads ----
    const ushort* kb = k + (size_t)b * GRID_S * FDIM + 8 * lane;
    float sc[KNN];
    #pragma unroll
    for (int j = 0; j < KNN; ++j) {
        const uint4 kw = *(const uint4*)(kb + ((size_t)(uint32_t)nrow[j] << 9));
        f32x2 a2 = q2[0] * unpk(kw.x);
        a2 = FMA2(q2[1], unpk(kw.y), a2);
        a2 = FMA2(q2[2], unpk(kw.z), a2);
        a2 = FMA2(q2[3], unpk(kw.w), a2);
        float p = a2.x + a2.y;
        p += __shfl_xor(p, 1);
        p += __shfl_xor(p, 2);
        p += __shfl_xor(p, 4);
        sc[j] = p;           // all lanes of head group h hold score[h][j]
    }

    // ---- per-lane register softmax (unnormalized; 1/sum folded into epilogue) ----
    float mx = sc[0];
    #pragma unroll
    for (int j = 1; j < KNN; ++j) mx = fmaxf(mx, sc[j]);
    float sum = 0.f;
    #pragma unroll
    for (int j = 0; j < KNN; ++j) {
        sc[j] = __expf(sc[j] - mx);
        sum += sc[j];
    }
    const float inv = 1.0f / sum;

    // ---- PV: 32 coalesced row reads, weights in-lane ----
    const ushort* vb = v + (size_t)b * GRID_S * FDIM + 8 * lane;
    f32x2 acc[4] = {};
    #pragma unroll
    for (int j = 0; j < KNN; ++j) {
        const uint4 vw = *(const uint4*)(vb + ((size_t)(uint32_t)nrow[j] << 9));
        const f32x2 w2 = {sc[j], sc[j]};
        acc[0] = FMA2(w2, unpk(vw.x), acc[0]);
        acc[1] = FMA2(w2, unpk(vw.y), acc[1]);
        acc[2] = FMA2(w2, unpk(vw.z), acc[2]);
        acc[3] = FMA2(w2, unpk(vw.w), acc[3]);
    }
    const f32x2 inv2 = {inv, inv};
    #pragma unroll
    for (int r = 0; r < 4; ++r) acc[r] *= inv2;

    float* op = out + (size_t)bs * FDIM + 8 * lane;
    float4 o0 = {acc[0].x, acc[0].y, acc[1].x, acc[1].y};
    float4 o1 = {acc[2].x, acc[2].y, acc[3].x, acc[3].y};
    *(float4*)op = o0;
    *(float4*)(op + 4) = o1;
}

extern "C" void kernel_launch(void* const* d_in, const int* in_sizes, int n_in,
                              void* d_out, int out_size, void* d_ws, size_t ws_size,
                              hipStream_t stream) {
    const float* x  = (const float*)d_in[0];
    const float* Wq = (const float*)d_in[1];
    const float* Wk = (const float*)d_in[2];
    const float* Wv = (const float*)d_in[3];
    const int*   nbr = (const int*)d_in[4];
    float* out = (float*)d_out;

    const size_t m_elems = (size_t)M_TOT * FDIM;
    const size_t w_elems = (size_t)FDIM * FDIM;

    ushort* xb  = (ushort*)d_ws;
    ushort* wb  = xb + m_elems;
    ushort* kbf = wb + 3 * w_elems;
    ushort* vbf = kbf + m_elems;
    float*  qp  = out;   // q staged in d_out (each wave reads then rewrites only its own row)

    cvt_all<<<(NX4 + 3 * NW4) / 256, 256, 0, stream>>>(x, Wq, Wk, Wv, xb, wb);

    dim3 grid(M_TOT / TBM, 3 * FDIM / TBN);   // (250, 12)
    gemm_qkv<<<grid, 256, 0, stream>>>(xb, wb, qp, kbf, vbf);

    knn_attn4<<<M_TOT / 4, 256, 0, stream>>>(qp, kbf, vbf, nbr, out);
}

// Round 6
// 214.157 us; speedup vs baseline: 5.1759x; 1.0017x over previous
//
#include <hip/hip_runtime.h>
#include <cstddef>
#include <cstdint>

#define GRID_S 8000
#define FDIM 512
#define NHEAD 8
#define HD 64
#define KNN 32
#define NB 4
#define M_TOT (NB * GRID_S)   // 32000

typedef __attribute__((ext_vector_type(8))) __bf16 bf16x8;
typedef __attribute__((ext_vector_type(4))) float f32x4;
typedef __attribute__((ext_vector_type(2))) float f32x2;
typedef __attribute__((ext_vector_type(2))) short short2v;

#if __has_builtin(__builtin_elementwise_fma)
#define FMA2(a,b,c) __builtin_elementwise_fma((a),(b),(c))
#else
#define FMA2(a,b,c) ((a)*(b)+(c))
#endif

#if __has_builtin(__builtin_amdgcn_fdot2_f32_bf16)
#define HAS_DOT2 1
#else
#define HAS_DOT2 0
#endif

// ---------------- helpers ----------------
__device__ inline ushort f2bf(float f) {            // RTN-even
    uint32_t u = __builtin_bit_cast(uint32_t, f);
    uint32_t r = (u + 0x7fffu + ((u >> 16) & 1u)) >> 16;
    return (ushort)r;
}
__device__ inline f32x2 unpk(uint32_t u) {          // packed bf16 pair -> 2 floats
    f32x2 r;
    r.x = __builtin_bit_cast(float, u << 16);
    r.y = __builtin_bit_cast(float, u & 0xffff0000u);
    return r;
}

// ---------------- fused fp32->bf16 convert ----------------
#define NX4 (M_TOT * FDIM / 4)   // 4,096,000
#define NW4 (FDIM * FDIM / 4)    // 65,536

__global__ __launch_bounds__(256) void cvt_all(const float* __restrict__ x,
                                               const float* __restrict__ Wq,
                                               const float* __restrict__ Wk,
                                               const float* __restrict__ Wv,
                                               ushort* __restrict__ xb,
                                               ushort* __restrict__ wb) {
    int i = blockIdx.x * 256 + threadIdx.x;
    if (i < NX4) {
        float4 f = ((const float4*)x)[i];
        ushort4 o = { f2bf(f.x), f2bf(f.y), f2bf(f.z), f2bf(f.w) };
        ((ushort4*)xb)[i] = o;
        return;
    }
    i -= NX4;
    const int which = i >> 16;
    const int off = i & (NW4 - 1);
    const float* w = (which == 0) ? Wq : (which == 1) ? Wk : Wv;
    float4 f = ((const float4*)w)[off];
    ushort4 o = { f2bf(f.x), f2bf(f.y), f2bf(f.z), f2bf(f.w) };
    ((ushort4*)wb)[which * NW4 + off] = o;
}

// ---------------- fused QKV bf16 MFMA GEMM ----------------
// All three outputs bf16; q gets the Hd^-0.5 = 0.125 scale folded in (exact pow2).
#define TBM 128
#define TBN 128
#define TBK 32

__device__ inline void gload_lds16(const ushort* g, ushort* l) {
    __builtin_amdgcn_global_load_lds((const __attribute__((address_space(1))) uint32_t*)g,
                                     (__attribute__((address_space(3))) uint32_t*)l,
                                     16, 0, 0);
}

__global__ __launch_bounds__(256) void gemm_qkv(const ushort* __restrict__ A,
                                                const ushort* __restrict__ B,
                                                ushort* __restrict__ qo,
                                                ushort* __restrict__ ko,
                                                ushort* __restrict__ vo) {
    __shared__ ushort As[TBM * TBK];
    __shared__ ushort Bs[TBN * TBK];
    const int tid = threadIdx.x;
    const int wv = tid >> 6;
    const int lane = tid & 63;
    const int bm = blockIdx.x * TBM;
    const int bn = blockIdx.y * TBN;
    const int wr = (wv >> 1) * 64;
    const int wc = (wv & 1) * 64;
    f32x4 acc[4][4] = {};

    const int srow = wv * 32 + (lane >> 2);
    const int scol = (lane & 3) * 8;
    const int fr = lane & 15;
    const int fk = (lane >> 4) * 8;

    for (int k0 = 0; k0 < FDIM; k0 += TBK) {
        const ushort* ga = A + (size_t)(bm + srow) * FDIM + k0 + scol;
        const ushort* gb = B + (size_t)(bn + srow) * FDIM + k0 + scol;
        gload_lds16(ga,             &As[(wv * 32) * TBK]);
        gload_lds16(ga + 16 * FDIM, &As[(wv * 32 + 16) * TBK]);
        gload_lds16(gb,             &Bs[(wv * 32) * TBK]);
        gload_lds16(gb + 16 * FDIM, &Bs[(wv * 32 + 16) * TBK]);
        __syncthreads();

        bf16x8 af[4], bfr[4];
        #pragma unroll
        for (int i = 0; i < 4; ++i) {
            af[i]  = *(const bf16x8*)&As[(wr + i * 16 + fr) * TBK + fk];
            bfr[i] = *(const bf16x8*)&Bs[(wc + i * 16 + fr) * TBK + fk];
        }
        #pragma unroll
        for (int i = 0; i < 4; ++i)
            #pragma unroll
            for (int j = 0; j < 4; ++j)
                acc[i][j] = __builtin_amdgcn_mfma_f32_16x16x32_bf16(af[i], bfr[j], acc[i][j], 0, 0, 0);
        __syncthreads();
    }

    const int cr = (lane >> 4) * 4;
    const int cc = lane & 15;
    const int seg = blockIdx.y >> 2;                  // 0=q, 1=k, 2=v
    const int cn = (blockIdx.y & 3) * TBN;
    ushort* dst = (seg == 0) ? qo : (seg == 1) ? ko : vo;
    const float scl = (seg == 0) ? 0.125f : 1.0f;     // fold Hd^-0.5 into q
    #pragma unroll
    for (int i = 0; i < 4; ++i)
        #pragma unroll
        for (int j = 0; j < 4; ++j) {
            ushort* cp = dst + (size_t)(bm + wr + i * 16 + cr) * FDIM + cn + wc + j * 16 + cc;
            #pragma unroll
            for (int r = 0; r < 4; ++r)
                cp[(size_t)r * FDIM] = f2bf(acc[i][j][r] * scl);
        }
}

// ---------------- KNN attention v5: wave-per-s, bf16 dot2 scoring ----------------
// lane l owns features [8l, 8l+8); 8-lane group = one head.
// scoring: v_dot2_f32_bf16 on packed bf16 q x k (4 insts / 16B), 3-shfl reduce.
// softmax: per-lane registers; 1/sum folded into epilogue.
// PV: unpack + packed f32 FMA, weights in-lane. No LDS, no barriers.
__global__ __launch_bounds__(256) void knn_attn5(const ushort* __restrict__ q,
                                                 const ushort* __restrict__ k,
                                                 const ushort* __restrict__ v,
                                                 const int* __restrict__ nbr,
                                                 float* __restrict__ out) {
    const int bid = blockIdx.x;
    const int base = ((bid & 7) * (M_TOT / 32) + (bid >> 3)) * 4;   // bijective XCD swizzle
    const int lane = threadIdx.x & 63;
    const int wv = threadIdx.x >> 6;
    const int bs = base + wv;
    const int b = bs / GRID_S;
    const int s = bs - b * GRID_S;
    const int* __restrict__ nrow = nbr + s * KNN;   // wave-uniform -> scalar loads

    // q fragment: 8 bf16, already scaled by 0.125
    const uint4 qw = *(const uint4*)(q + (size_t)bs * FDIM + 8 * lane);
#if HAS_DOT2
    const short2v qs0 = __builtin_bit_cast(short2v, qw.x);
    const short2v qs1 = __builtin_bit_cast(short2v, qw.y);
    const short2v qs2 = __builtin_bit_cast(short2v, qw.z);
    const short2v qs3 = __builtin_bit_cast(short2v, qw.w);
#else
    const f32x2 q2[4] = { unpk(qw.x), unpk(qw.y), unpk(qw.z), unpk(qw.w) };
#endif

    // ---- scoring: 32 coalesced row reads ----
    const ushort* kb = k + (size_t)b * GRID_S * FDIM + 8 * lane;
    float sc[KNN];
    #pragma unroll
    for (int j = 0; j < KNN; ++j) {
        const uint4 kw = *(const uint4*)(kb + ((size_t)(uint32_t)nrow[j] << 9));
#if HAS_DOT2
        float p = __builtin_amdgcn_fdot2_f32_bf16(__builtin_bit_cast(short2v, kw.x), qs0, 0.f, false);
        p = __builtin_amdgcn_fdot2_f32_bf16(__builtin_bit_cast(short2v, kw.y), qs1, p, false);
        p = __builtin_amdgcn_fdot2_f32_bf16(__builtin_bit_cast(short2v, kw.z), qs2, p, false);
        p = __builtin_amdgcn_fdot2_f32_bf16(__builtin_bit_cast(short2v, kw.w), qs3, p, false);
#else
        f32x2 a2 = q2[0] * unpk(kw.x);
        a2 = FMA2(q2[1], unpk(kw.y), a2);
        a2 = FMA2(q2[2], unpk(kw.z), a2);
        a2 = FMA2(q2[3], unpk(kw.w), a2);
        float p = a2.x + a2.y;
#endif
        p += __shfl_xor(p, 1);
        p += __shfl_xor(p, 2);
        p += __shfl_xor(p, 4);
        sc[j] = p;
    }

    // ---- per-lane register softmax ----
    float mx = sc[0];
    #pragma unroll
    for (int j = 1; j < KNN; ++j) mx = fmaxf(mx, sc[j]);
    float sum = 0.f;
    #pragma unroll
    for (int j = 0; j < KNN; ++j) {
        sc[j] = __expf(sc[j] - mx);
        sum += sc[j];
    }
    const float inv = 1.0f / sum;

    // ---- PV: 32 coalesced row reads, weights in-lane ----
    const ushort* vb = v + (size_t)b * GRID_S * FDIM + 8 * lane;
    f32x2 acc[4] = {};
    #pragma unroll
    for (int j = 0; j < KNN; ++j) {
        const uint4 vw = *(const uint4*)(vb + ((size_t)(uint32_t)nrow[j] << 9));
        const f32x2 w2 = {sc[j], sc[j]};
        acc[0] = FMA2(w2, unpk(vw.x), acc[0]);
        acc[1] = FMA2(w2, unpk(vw.y), acc[1]);
        acc[2] = FMA2(w2, unpk(vw.z), acc[2]);
        acc[3] = FMA2(w2, unpk(vw.w), acc[3]);
    }
    const f32x2 inv2 = {inv, inv};
    #pragma unroll
    for (int r = 0; r < 4; ++r) acc[r] *= inv2;

    float* op = out + (size_t)bs * FDIM + 8 * lane;
    float4 o0 = {acc[0].x, acc[0].y, acc[1].x, acc[1].y};
    float4 o1 = {acc[2].x, acc[2].y, acc[3].x, acc[3].y};
    *(float4*)op = o0;
    *(float4*)(op + 4) = o1;
}

extern "C" void kernel_launch(void* const* d_in, const int* in_sizes, int n_in,
                              void* d_out, int out_size, void* d_ws, size_t ws_size,
                              hipStream_t stream) {
    const float* x  = (const float*)d_in[0];
    const float* Wq = (const float*)d_in[1];
    const float* Wk = (const float*)d_in[2];
    const float* Wv = (const float*)d_in[3];
    const int*   nbr = (const int*)d_in[4];
    float* out = (float*)d_out;

    const size_t m_elems = (size_t)M_TOT * FDIM;   // 16,384,000
    const size_t w_elems = (size_t)FDIM * FDIM;    // 262,144

    // workspace (bf16): xb, wb[3], k, v, q  ~= 100 MB
    ushort* xb  = (ushort*)d_ws;
    ushort* wb  = xb + m_elems;
    ushort* kbf = wb + 3 * w_elems;
    ushort* vbf = kbf + m_elems;
    ushort* qbf = vbf + m_elems;

    cvt_all<<<(NX4 + 3 * NW4) / 256, 256, 0, stream>>>(x, Wq, Wk, Wv, xb, wb);

    dim3 grid(M_TOT / TBM, 3 * FDIM / TBN);   // (250, 12)
    gemm_qkv<<<grid, 256, 0, stream>>>(xb, wb, qbf, kbf, vbf);

    knn_attn5<<<M_TOT / 4, 256, 0, stream>>>(qbf, kbf, vbf, nbr, out);
}